// Round 7
// baseline (969.156 us; speedup 1.0000x reference)
//
#include <hip/hip_runtime.h>
#include <math.h>

// FineGrainedRetriever round 7: barrier-free GEMMs. A-fragments are loaded
// DIRECTLY from global memory (row-major k-contiguous => one 16B load per
// fragment, same [k-window][idx][8] packing on A and B sides -> k-permutation
// invariant). No LDS, no __syncthreads in k_gemm; latency hidden by TLP +
// 8-deep per-wave load ILP. Epilogues/gathers/CSR unchanged from round 6.

namespace {
constexpr int E    = 200000;
constexpr int NV   = 50000;
constexpr int D    = 256;
constexpr int TWOE = 2 * E;
}

typedef __attribute__((ext_vector_type(8))) _Float16 f16x8;
typedef __attribute__((ext_vector_type(4))) _Float16 f16x4;
typedef __attribute__((ext_vector_type(16))) float f32x16;

#define MFMA16(a, b, c) __builtin_amdgcn_mfma_f32_32x32x16_f16((a), (b), (c), 0, 0, 0)

// ---- edge_index dtype probe (int64 vs int32) -------------------------------
__global__ void k_detect(const void* ei_raw, int* flag) {
  __shared__ int bad;
  if (threadIdx.x == 0) bad = 0;
  __syncthreads();
  const long long* p = (const long long*)ei_raw;
  long long v = p[threadIdx.x];
  if (v < 0 || v >= (long long)NV) atomicOr(&bad, 1);
  __syncthreads();
  if (threadIdx.x == 0) *flag = bad ? 0 : 1;  // 1 => int64
}

__global__ void k_convert(const void* ei_raw, const int* __restrict__ flag,
                          int* __restrict__ ei32) {
  int i = blockIdx.x * 256 + threadIdx.x;
  if (i >= TWOE) return;
  if (*flag) ei32[i] = (int)((const long long*)ei_raw)[i];
  else       ei32[i] = ((const int*)ei_raw)[i];
}

// ---- CSR build -------------------------------------------------------------
__global__ void k_deg(const int* __restrict__ ei32, int* __restrict__ deg) {
  int de = blockIdx.x * 256 + threadIdx.x;
  if (de >= TWOE) return;
  int dst = (de < E) ? ei32[E + de] : ei32[de - E];
  atomicAdd(&deg[dst], 1);
}

__global__ __launch_bounds__(1024) void k_scan(const int* __restrict__ deg,
                                               int* __restrict__ off) {
  __shared__ int wsum[16];
  __shared__ int carryS;
  int tid = threadIdx.x;
  int lane = tid & 63, wv = tid >> 6;
  if (tid == 0) carryS = 0;
  __syncthreads();
  for (int base = 0; base < NV; base += 1024) {
    int i = base + tid;
    int v = (i < NV) ? deg[i] : 0;
    int s = v;
#pragma unroll
    for (int d = 1; d < 64; d <<= 1) {
      int t = __shfl_up(s, d);
      if (lane >= d) s += t;
    }
    if (lane == 63) wsum[wv] = s;
    int carry = carryS;
    __syncthreads();
    if (wv == 0) {
      int ws = (lane < 16) ? wsum[lane] : 0;
#pragma unroll
      for (int d = 1; d < 16; d <<= 1) {
        int t = __shfl_up(ws, d);
        if (lane >= d) ws += t;
      }
      if (lane < 16) wsum[lane] = ws;
    }
    __syncthreads();
    int wexcl = (wv == 0) ? 0 : wsum[wv - 1];
    if (i < NV) off[i] = carry + wexcl + s - v;
    if (tid == 1023) carryS = carry + wsum[15];
    __syncthreads();
  }
  if (tid == 0) off[NV] = carryS;
}

__global__ void k_fill(const int* __restrict__ ei32, const int* __restrict__ off,
                       int* __restrict__ cursor, int* __restrict__ eidA,
                       int* __restrict__ srcA) {
  int de = blockIdx.x * 256 + threadIdx.x;
  if (de >= TWOE) return;
  int dst = (de < E) ? ei32[E + de] : ei32[de - E];
  int p = atomicAdd(&cursor[dst], 1);
  int idx = off[dst] + p;
  eidA[idx] = de;
  srcA[idx] = ei32[de];
}

__global__ void k_rinv(const int* __restrict__ off, float* __restrict__ rinv) {
  int n = blockIdx.x * 256 + threadIdx.x;
  if (n < NV) {
    int d = off[n + 1] - off[n];
    rinv[n] = 1.f / fmaxf((float)d, 1.f);
  }
}

// ---- f32 -> f16 copy (8 elems/thread) --------------------------------------
__global__ void k_conv16(const float* __restrict__ x, _Float16* __restrict__ y,
                         int n8) {
  int i = blockIdx.x * 256 + threadIdx.x;
  if (i >= n8) return;
  const float4* p = (const float4*)x;
  float4 a = p[2 * i], b = p[2 * i + 1];
  f16x8 o;
  o[0] = (_Float16)a.x; o[1] = (_Float16)a.y; o[2] = (_Float16)a.z; o[3] = (_Float16)a.w;
  o[4] = (_Float16)b.x; o[5] = (_Float16)b.y; o[6] = (_Float16)b.z; o[7] = (_Float16)b.w;
  ((f16x8*)y)[i] = o;
}

// ---- gather: hsum[n] = sum fwd ea rows (f32); hid16 = sum rev hid; degrev --
__global__ __launch_bounds__(256) void k_gath_h(
    const float* __restrict__ ea, const _Float16* __restrict__ tmp16,
    const int* __restrict__ eidA, const int* __restrict__ off,
    float* __restrict__ hsum, _Float16* __restrict__ hid16,
    float* __restrict__ degrev) {
  int n = blockIdx.x * 4 + (threadIdx.x >> 6);
  if (n >= NV) return;
  int l = threadIdx.x & 63;
  float4 fs = {0.f, 0.f, 0.f, 0.f}, hv = {0.f, 0.f, 0.f, 0.f};
  int o0 = off[n], o1 = off[n + 1];
  int dr = 0;
  for (int j = o0; j < o1; j++) {
    int de = eidA[j];
    if (de < E) {
      float4 v = ((const float4*)(ea + (size_t)de * D))[l];
      fs.x += v.x; fs.y += v.y; fs.z += v.z; fs.w += v.w;
    } else {
      f16x4 v = ((const f16x4*)(tmp16 + (size_t)(de - E) * D))[l];
      hv.x += (float)v[0]; hv.y += (float)v[1];
      hv.z += (float)v[2]; hv.w += (float)v[3];
      dr++;
    }
  }
  ((float4*)(hsum + (size_t)n * D))[l] = fs;
  f16x4 ho;
  ho[0] = (_Float16)hv.x; ho[1] = (_Float16)hv.y;
  ho[2] = (_Float16)hv.z; ho[3] = (_Float16)hv.w;
  ((f16x4*)(hid16 + (size_t)n * D))[l] = ho;
  if (l == 0) degrev[n] = (float)dr;
}

// ---- per-layer aggregate: agg16[n] = (sum_j x16[src_j] + hsum[n])*rinv[n] --
__global__ __launch_bounds__(256) void k_agg(
    const _Float16* __restrict__ x16, const int* __restrict__ srcA,
    const int* __restrict__ off, const float* __restrict__ hsum,
    const float* __restrict__ rinv, _Float16* __restrict__ agg16) {
  int n = blockIdx.x * 4 + (threadIdx.x >> 6);
  if (n >= NV) return;
  int l = threadIdx.x & 63;
  float4 s = ((const float4*)(hsum + (size_t)n * D))[l];
  int o0 = off[n], o1 = off[n + 1];
  for (int j = o0; j < o1; j++) {
    int src = srcA[j];
    f16x4 v = ((const f16x4*)(x16 + (size_t)src * D))[l];
    s.x += (float)v[0]; s.y += (float)v[1];
    s.z += (float)v[2]; s.w += (float)v[3];
  }
  float r = rinv[n];
  f16x4 o;
  o[0] = (_Float16)(s.x * r); o[1] = (_Float16)(s.y * r);
  o[2] = (_Float16)(s.z * r); o[3] = (_Float16)(s.w * r);
  ((f16x4*)(agg16 + (size_t)n * D))[l] = o;
}

// ---- weight prep: W[K][256] f32 -> Wf [K/8][256][8] f16 --------------------
__global__ __launch_bounds__(256) void k_wprep(const float* __restrict__ W,
                                               _Float16* __restrict__ Wf) {
  __shared__ float tl[32][260];
  int tid = threadIdx.x;
  int k0 = blockIdx.x * 32;
#pragma unroll
  for (int i = 0; i < 32; i++) tl[i][tid] = W[(size_t)(k0 + i) * 256 + tid];
  __syncthreads();
  f16x8* WfV = (f16x8*)Wf;
#pragma unroll
  for (int kg = 0; kg < 4; kg++) {
    f16x8 p;
#pragma unroll
    for (int j = 0; j < 8; j++) p[j] = (_Float16)tl[kg * 8 + j][tid];
    WfV[(size_t)((k0 >> 3) + kg) * 256 + tid] = p;
  }
}

// ---- qW[n] = q @ pred_W1[:256,n] + pred_b1[n] ------------------------------
__global__ void k_qw(const float* __restrict__ q, const float* __restrict__ W1,
                     const float* __restrict__ b1, float* __restrict__ qW) {
  __shared__ float ql[D];
  int n = threadIdx.x;
  ql[n] = q[n];
  __syncthreads();
  float s = b1[n];
  for (int k = 0; k < D; k++) s += ql[k] * W1[(size_t)k * D + n];
  qW[n] = s;
}

// ---- generic f16 MFMA GEMM, barrier-free, direct A-frag loads --------------
enum AM { AF32, AF16, AF16D };
enum EP { EP_RELU16, EP_ADDC, EP_HE2, EP_PROJ2 };

template<int AMODE>
__device__ inline f16x8 loadAfrag(const void* Av0, const void* Av1,
                                  int row, int k) {
  if (AMODE == AF32) {
    const float* src = (const float*)Av0 + (size_t)row * 256 + k;
    float4 a = ((const float4*)src)[0], b = ((const float4*)src)[1];
    f16x8 p;
    p[0] = (_Float16)a.x; p[1] = (_Float16)a.y;
    p[2] = (_Float16)a.z; p[3] = (_Float16)a.w;
    p[4] = (_Float16)b.x; p[5] = (_Float16)b.y;
    p[6] = (_Float16)b.z; p[7] = (_Float16)b.w;
    return p;
  }
  const _Float16* base =
      (AMODE == AF16D && k >= 256)
          ? ((const _Float16*)Av1 + (size_t)row * 256 + (k - 256))
          : ((const _Float16*)Av0 + (size_t)row * 256 + k);
  return *(const f16x8*)base;
}

template<int AMODE, int EPI>
__global__ __launch_bounds__(256) void k_gemm(
    const void* Av0, const void* Av1,
    const float* __restrict__ addm, const float* __restrict__ rv,
    const _Float16* __restrict__ Wf, const _Float16* __restrict__ Wf2,
    const float* __restrict__ bias, const float* __restrict__ qW,
    float* __restrict__ outf, _Float16* __restrict__ o16a,
    _Float16* __restrict__ o16b, int M, int K) {
  constexpr bool DUAL = (EPI == EP_HE2 || EPI == EP_PROJ2);
  const int tid = threadIdx.x;
  const int w = tid >> 6;
  const int lane31 = tid & 31;
  const int hw = (tid >> 5) & 1;
  const int m0 = blockIdx.x * 64;
  const int col0 = (w << 6) + lane31;   // 0..255
  const int col1 = col0 + 32;
  const int rowA = m0 + lane31;         // this lane's A rows
  const int rowB = rowA + 32;

  f32x16 acc[2][2], acc2[2][2];
#pragma unroll
  for (int a = 0; a < 2; a++)
#pragma unroll
    for (int b = 0; b < 2; b++)
#pragma unroll
      for (int i = 0; i < 16; i++) { acc[a][b][i] = 0.f; acc2[a][b][i] = 0.f; }

  const f16x8* WV  = (const f16x8*)Wf;
  const f16x8* WV2 = (const f16x8*)Wf2;

  const int nt = K >> 6;
#pragma unroll 2
  for (int t = 0; t < nt; ++t) {
    const int k0 = t * 64;
    // preload this K-step's 8 A-fragments (independent 16B loads)
    f16x8 a0f[4], a1f[4];
#pragma unroll
    for (int ks = 0; ks < 4; ks++) {
      const int kk = k0 + (2 * ks + hw) * 8;
      a0f[ks] = loadAfrag<AMODE>(Av0, Av1, rowA, kk);
      a1f[ks] = loadAfrag<AMODE>(Av0, Av1, rowB, kk);
    }
#pragma unroll
    for (int ks = 0; ks < 4; ks++) {
      const int kgl = 2 * ks + hw;
      size_t wi = (size_t)((k0 >> 3) + kgl) * 256;
      f16x8 b0 = WV[wi + col0];
      f16x8 b1 = WV[wi + col1];
      acc[0][0] = MFMA16(a0f[ks], b0, acc[0][0]);
      acc[0][1] = MFMA16(a0f[ks], b1, acc[0][1]);
      acc[1][0] = MFMA16(a1f[ks], b0, acc[1][0]);
      acc[1][1] = MFMA16(a1f[ks], b1, acc[1][1]);
      if (DUAL) {
        f16x8 c0 = WV2[wi + col0];
        f16x8 c1 = WV2[wi + col1];
        acc2[0][0] = MFMA16(a0f[ks], c0, acc2[0][0]);
        acc2[0][1] = MFMA16(a0f[ks], c1, acc2[0][1]);
        acc2[1][0] = MFMA16(a1f[ks], c0, acc2[1][0]);
        acc2[1][1] = MFMA16(a1f[ks], c1, acc2[1][1]);
      }
    }
  }

  if (EPI == EP_RELU16) {
    float b0v = bias[col0], b1v = bias[col1];
#pragma unroll
    for (int rf = 0; rf < 2; rf++)
#pragma unroll
      for (int g = 0; g < 4; g++)
#pragma unroll
        for (int qq = 0; qq < 4; qq++) {
          int row = m0 + 32 * rf + qq + 8 * g + 4 * hw;
          if (row < M) {
            o16a[(size_t)row * 256 + col0] =
                (_Float16)fmaxf(acc[rf][0][4 * g + qq] + b0v, 0.f);
            o16a[(size_t)row * 256 + col1] =
                (_Float16)fmaxf(acc[rf][1][4 * g + qq] + b1v, 0.f);
          }
        }
  }
  if (EPI == EP_ADDC) {
    float b0v = bias[col0], b1v = bias[col1];
#pragma unroll
    for (int rf = 0; rf < 2; rf++)
#pragma unroll
      for (int g = 0; g < 4; g++)
#pragma unroll
        for (int qq = 0; qq < 4; qq++) {
          int row = m0 + 32 * rf + qq + 8 * g + 4 * hw;
          if (row < M) {
            float dr = rv[row];
            outf[(size_t)row * 256 + col0] =
                acc[rf][0][4 * g + qq] + addm[(size_t)row * 256 + col0] + dr * b0v;
            outf[(size_t)row * 256 + col1] =
                acc[rf][1][4 * g + qq] + addm[(size_t)row * 256 + col1] + dr * b1v;
          }
        }
  }
  if (EPI == EP_HE2) {
#pragma unroll
    for (int rf = 0; rf < 2; rf++)
#pragma unroll
      for (int g = 0; g < 4; g++)
#pragma unroll
        for (int qq = 0; qq < 4; qq++) {
          int row = m0 + 32 * rf + qq + 8 * g + 4 * hw;
          if (row < M) {
            o16a[(size_t)row * 256 + col0] = (_Float16)acc[rf][0][4 * g + qq];
            o16a[(size_t)row * 256 + col1] = (_Float16)acc[rf][1][4 * g + qq];
            o16b[(size_t)row * 256 + col0] = (_Float16)acc2[rf][0][4 * g + qq];
            o16b[(size_t)row * 256 + col1] = (_Float16)acc2[rf][1][4 * g + qq];
          }
        }
  }
  if (EPI == EP_PROJ2) {
    float b0v = bias[col0], b1v = bias[col1];
    float q0 = qW[col0], q1 = qW[col1];
#pragma unroll
    for (int rf = 0; rf < 2; rf++)
#pragma unroll
      for (int g = 0; g < 4; g++)
#pragma unroll
        for (int qq = 0; qq < 4; qq++) {
          int row = m0 + 32 * rf + qq + 8 * g + 4 * hw;
          if (row < M) {
            o16a[(size_t)row * 256 + col0] =
                (_Float16)fmaxf(acc[rf][0][4 * g + qq] + b0v, 0.f);
            o16a[(size_t)row * 256 + col1] =
                (_Float16)fmaxf(acc[rf][1][4 * g + qq] + b1v, 0.f);
            o16b[(size_t)row * 256 + col0] = (_Float16)(acc2[rf][0][4 * g + qq] + q0);
            o16b[(size_t)row * 256 + col1] = (_Float16)(acc2[rf][1][4 * g + qq] + q1);
          }
        }
  }
}

// ---- lean edge combine: logits/sampled from ea2q16 + HEh/HEt gathers -------
__global__ __launch_bounds__(256) void k_edge(
    const _Float16* __restrict__ ea2q, const _Float16* __restrict__ HEh,
    const _Float16* __restrict__ HEt, const int* __restrict__ ei32,
    const float* __restrict__ pW2, const float* __restrict__ pb2,
    const float* __restrict__ noise, float* __restrict__ dout) {
  int e = blockIdx.x * 4 + (threadIdx.x >> 6);
  int l = threadIdx.x & 63;
  int h = ei32[e], t = ei32[E + e];
  f16x4 a  = ((const f16x4*)(ea2q + (size_t)e * 256))[l];
  f16x4 hv = ((const f16x4*)(HEh + (size_t)h * 256))[l];
  f16x4 tv = ((const f16x4*)(HEt + (size_t)t * 256))[l];
  float4 wv = ((const float4*)pW2)[l];
  float s = fmaxf((float)a[0] + (float)hv[0] + (float)tv[0], 0.f) * wv.x
          + fmaxf((float)a[1] + (float)hv[1] + (float)tv[1], 0.f) * wv.y
          + fmaxf((float)a[2] + (float)hv[2] + (float)tv[2], 0.f) * wv.z
          + fmaxf((float)a[3] + (float)hv[3] + (float)tv[3], 0.f) * wv.w;
#pragma unroll
  for (int m = 1; m <= 32; m <<= 1) s += __shfl_xor(s, m);
  if (l == 0) {
    float lg = s + pb2[0];
    float nz = noise[e];
    float rn = logf(nz) - logf(1.f - nz);
    dout[e] = lg;
    dout[E + e] = 1.f / (1.f + expf(-(lg + rn)));
  }
}

extern "C" void kernel_launch(void* const* d_in, const int* in_sizes, int n_in,
                              void* d_out, int out_size, void* d_ws, size_t ws_size,
                              hipStream_t stream) {
  const float* entity = (const float*)d_in[0];
  const float* ea     = (const float*)d_in[1];
  const float* q      = (const float*)d_in[2];
  const float* noise  = (const float*)d_in[3];
  const float* W_pr1  = (const float*)d_in[4];
  const float* b_pr1  = (const float*)d_in[5];
  const float* W_pr2  = (const float*)d_in[6];
  const float* b_pr2  = (const float*)d_in[7];
  const float* sW0    = (const float*)d_in[8];
  const float* sb0    = (const float*)d_in[9];
  const float* sW1    = (const float*)d_in[10];
  const float* sb1    = (const float*)d_in[11];
  const float* pW1    = (const float*)d_in[12];
  const float* pb1    = (const float*)d_in[13];
  const float* pW2    = (const float*)d_in[14];
  const float* pb2    = (const float*)d_in[15];
  const void*  ei_raw = d_in[16];

  char* ws = (char*)d_ws;
  const size_t EDH = (size_t)E * D * 2;    // 102.4 MB f16 edge matrix
  const size_t NDB = (size_t)NV * D * 4;   // 51.2 MB f32 node matrix
  const size_t NDH = (size_t)NV * D * 2;   // 25.6 MB f16 node matrix
  const size_t PAD = 64 * 256 * 2;         // OOB tile-read slack (32 KB)
  size_t off_b = 0;
  char* r1a = ws + off_b; off_b += EDH + PAD;        // tmp16
  char* r1b = ws + off_b; off_b += EDH + PAD;        // ea2q16
  char* r2  = ws + off_b; off_b += NDB + PAD;        // hsum f32 -> HEh16|HEt16
  char* r3  = ws + off_b; off_b += NDH + PAD;        // hid16 -> agg16
  char* r4  = ws + off_b; off_b += NDH + PAD;        // ent16 -> out116
  char* r5  = ws + off_b; off_b += NDH + PAD;        // out016
  auto alloc_w = [&](int K) { _Float16* p = (_Float16*)(ws + off_b);
                              off_b += (size_t)K * 256 * 2; return p; };
  _Float16* Wpr1f = alloc_w(256);
  _Float16* Wpr2f = alloc_w(256);
  _Float16* sW0f  = alloc_w(512);
  _Float16* sW1f  = alloc_w(512);
  _Float16* Whehf = alloc_w(512);
  _Float16* Whetf = alloc_w(512);
  _Float16* Weaf  = alloc_w(256);
  float* rinv   = (float*)(ws + off_b); off_b += (size_t)NV * 4;
  float* degrev = (float*)(ws + off_b); off_b += (size_t)NV * 4;
  float* qW     = (float*)(ws + off_b); off_b += 1024;
  int*   ei32   = (int*)(ws + off_b);   off_b += (size_t)TWOE * 4;
  int*   eidA   = (int*)(ws + off_b);   off_b += (size_t)TWOE * 4;
  int*   srcA   = (int*)(ws + off_b);   off_b += (size_t)TWOE * 4;
  int*   offA   = (int*)(ws + off_b);   off_b += (size_t)(NV + 1) * 4;
  int*   deg    = (int*)(ws + off_b);   off_b += (size_t)NV * 4;
  int*   cursor = (int*)(ws + off_b);   off_b += (size_t)NV * 4;
  int*   flag   = (int*)(ws + off_b);   off_b += 64;

  // lifetime aliases
  _Float16* tmp16  = (_Float16*)r1a;         // PROJ2 -> gath_h
  _Float16* ea2q16 = (_Float16*)r1b;         // PROJ2 -> k_edge
  float*    hsum   = (float*)r2;             // gath -> ADDC -> agg0/agg1
  _Float16* HEh16  = (_Float16*)r2;          // HE2 -> k_edge
  _Float16* HEt16  = (_Float16*)(r2 + NDH);
  _Float16* hid16  = (_Float16*)r3;          // gath -> ADDC
  _Float16* agg16  = (_Float16*)r3;          // agg -> sage (per layer)
  _Float16* ent16  = (_Float16*)r4;          // conv -> agg0/sage0
  _Float16* out116 = (_Float16*)r4;          // sage1 -> HE2
  _Float16* out016 = (_Float16*)r5;          // sage0 -> agg1/sage1/HE2

  // ---- indices & CSR ----
  k_detect<<<1, 256, 0, stream>>>(ei_raw, flag);
  k_convert<<<(TWOE + 255) / 256, 256, 0, stream>>>(ei_raw, flag, ei32);
  hipMemsetAsync(deg, 0, (size_t)NV * 4, stream);
  hipMemsetAsync(cursor, 0, (size_t)NV * 4, stream);
  k_deg<<<(TWOE + 255) / 256, 256, 0, stream>>>(ei32, deg);
  k_scan<<<1, 1024, 0, stream>>>(deg, offA);
  k_fill<<<(TWOE + 255) / 256, 256, 0, stream>>>(ei32, offA, cursor, eidA, srcA);
  k_rinv<<<(NV + 255) / 256, 256, 0, stream>>>(offA, rinv);

  // ---- weight prep + shadows ----
  k_wprep<<<256 / 32, 256, 0, stream>>>(W_pr1, Wpr1f);
  k_wprep<<<256 / 32, 256, 0, stream>>>(W_pr2, Wpr2f);
  k_wprep<<<512 / 32, 256, 0, stream>>>(sW0, sW0f);
  k_wprep<<<512 / 32, 256, 0, stream>>>(sW1, sW1f);
  k_wprep<<<512 / 32, 256, 0, stream>>>(pW1 + 256 * 256, Whehf);
  k_wprep<<<512 / 32, 256, 0, stream>>>(pW1 + 1024 * 256, Whetf);
  k_wprep<<<256 / 32, 256, 0, stream>>>(pW1 + 768 * 256, Weaf);
  k_conv16<<<(NV * D / 8 + 255) / 256, 256, 0, stream>>>(entity, ent16, NV * D / 8);
  k_qw<<<1, 256, 0, stream>>>(q, pW1, pb1, qW);

  // ---- fused proj+EA2: tmp16 = relu(ea@Wpr1+b1); ea2q16 = ea@Wea + qW ----
  k_gemm<AF32, EP_PROJ2><<<E / 64, 256, 0, stream>>>(
      ea, nullptr, nullptr, nullptr, Wpr1f, Weaf, b_pr1, qW,
      nullptr, tmp16, ea2q16, E, 256);
  // gather: hsum = sum_fwd ea (f32); hid16 = sum_rev tmp16; degrev
  k_gath_h<<<(NV + 3) / 4, 256, 0, stream>>>(ea, tmp16, eidA, offA, hsum, hid16, degrev);
  // hsum += hid16 @ Wpr2 + degrev*b_pr2   (in place)
  k_gemm<AF16, EP_ADDC><<<(NV + 63) / 64, 256, 0, stream>>>(
      hid16, nullptr, hsum, degrev, Wpr2f, nullptr, b_pr2, nullptr,
      hsum, nullptr, nullptr, NV, 256);

  // ---- layer 0 ----
  k_agg<<<(NV + 3) / 4, 256, 0, stream>>>(ent16, srcA, offA, hsum, rinv, agg16);
  k_gemm<AF16D, EP_RELU16><<<(NV + 63) / 64, 256, 0, stream>>>(
      ent16, agg16, nullptr, nullptr, sW0f, nullptr, sb0, nullptr,
      nullptr, out016, nullptr, NV, 512);
  // ---- layer 1 ----
  k_agg<<<(NV + 3) / 4, 256, 0, stream>>>(out016, srcA, offA, hsum, rinv, agg16);
  k_gemm<AF16D, EP_RELU16><<<(NV + 63) / 64, 256, 0, stream>>>(
      out016, agg16, nullptr, nullptr, sW1f, nullptr, sb1, nullptr,
      nullptr, out116, nullptr, NV, 512);

  // ---- HE dual-weight GEMM: HEh16/HEt16 (into hsum region; hsum dead) ----
  k_gemm<AF16D, EP_HE2><<<(NV + 63) / 64, 256, 0, stream>>>(
      out016, out116, nullptr, nullptr, Whehf, Whetf, nullptr, nullptr,
      nullptr, HEh16, HEt16, NV, 512);

  // ---- lean edge combine ----
  k_edge<<<E / 4, 256, 0, stream>>>(ea2q16, HEh16, HEt16, ei32, pW2, pb2, noise,
                                    (float*)d_out);
}

// Round 8
// 844.516 us; speedup vs baseline: 1.1476x; 1.1476x over previous
//
#include <hip/hip_runtime.h>
#include <math.h>

// FineGrainedRetriever round 8: m97-style GEMM staging. All GEMM A-sources are
// f16 workspace buffers (ea pre-converted once). Per K-step the 64x64 f16
// A-tile is staged via global_load_lds (16B/lane, source-XOR-swizzled so
// global reads are 8x128B contiguous segments and ds_reads are ~conflict-free),
// double-buffered with the 2-phase loop: stage(next) -> compute(cur) -> barrier.
// Fragment layout, dual-weight fusion, CSR gathers, k_edge unchanged.

namespace {
constexpr int E    = 200000;
constexpr int NV   = 50000;
constexpr int D    = 256;
constexpr int TWOE = 2 * E;
}

typedef __attribute__((ext_vector_type(8))) _Float16 f16x8;
typedef __attribute__((ext_vector_type(4))) _Float16 f16x4;
typedef __attribute__((ext_vector_type(16))) float f32x16;

#define MFMA16(a, b, c) __builtin_amdgcn_mfma_f32_32x32x16_f16((a), (b), (c), 0, 0, 0)

typedef const __attribute__((address_space(1))) void* gas_t;
typedef __attribute__((address_space(3))) void* las_t;

__device__ inline void gload16(const void* g, void* l) {
  __builtin_amdgcn_global_load_lds((gas_t)g, (las_t)l, 16, 0, 0);
}

// ---- edge_index dtype probe (int64 vs int32) -------------------------------
__global__ void k_detect(const void* ei_raw, int* flag) {
  __shared__ int bad;
  if (threadIdx.x == 0) bad = 0;
  __syncthreads();
  const long long* p = (const long long*)ei_raw;
  long long v = p[threadIdx.x];
  if (v < 0 || v >= (long long)NV) atomicOr(&bad, 1);
  __syncthreads();
  if (threadIdx.x == 0) *flag = bad ? 0 : 1;  // 1 => int64
}

__global__ void k_convert(const void* ei_raw, const int* __restrict__ flag,
                          int* __restrict__ ei32) {
  int i = blockIdx.x * 256 + threadIdx.x;
  if (i >= TWOE) return;
  if (*flag) ei32[i] = (int)((const long long*)ei_raw)[i];
  else       ei32[i] = ((const int*)ei_raw)[i];
}

// ---- CSR build -------------------------------------------------------------
__global__ void k_deg(const int* __restrict__ ei32, int* __restrict__ deg) {
  int de = blockIdx.x * 256 + threadIdx.x;
  if (de >= TWOE) return;
  int dst = (de < E) ? ei32[E + de] : ei32[de - E];
  atomicAdd(&deg[dst], 1);
}

__global__ __launch_bounds__(1024) void k_scan(const int* __restrict__ deg,
                                               int* __restrict__ off) {
  __shared__ int wsum[16];
  __shared__ int carryS;
  int tid = threadIdx.x;
  int lane = tid & 63, wv = tid >> 6;
  if (tid == 0) carryS = 0;
  __syncthreads();
  for (int base = 0; base < NV; base += 1024) {
    int i = base + tid;
    int v = (i < NV) ? deg[i] : 0;
    int s = v;
#pragma unroll
    for (int d = 1; d < 64; d <<= 1) {
      int t = __shfl_up(s, d);
      if (lane >= d) s += t;
    }
    if (lane == 63) wsum[wv] = s;
    int carry = carryS;
    __syncthreads();
    if (wv == 0) {
      int ws = (lane < 16) ? wsum[lane] : 0;
#pragma unroll
      for (int d = 1; d < 16; d <<= 1) {
        int t = __shfl_up(ws, d);
        if (lane >= d) ws += t;
      }
      if (lane < 16) wsum[lane] = ws;
    }
    __syncthreads();
    int wexcl = (wv == 0) ? 0 : wsum[wv - 1];
    if (i < NV) off[i] = carry + wexcl + s - v;
    if (tid == 1023) carryS = carry + wsum[15];
    __syncthreads();
  }
  if (tid == 0) off[NV] = carryS;
}

__global__ void k_fill(const int* __restrict__ ei32, const int* __restrict__ off,
                       int* __restrict__ cursor, int* __restrict__ eidA,
                       int* __restrict__ srcA) {
  int de = blockIdx.x * 256 + threadIdx.x;
  if (de >= TWOE) return;
  int dst = (de < E) ? ei32[E + de] : ei32[de - E];
  int p = atomicAdd(&cursor[dst], 1);
  int idx = off[dst] + p;
  eidA[idx] = de;
  srcA[idx] = ei32[de];
}

__global__ void k_rinv(const int* __restrict__ off, float* __restrict__ rinv) {
  int n = blockIdx.x * 256 + threadIdx.x;
  if (n < NV) {
    int d = off[n + 1] - off[n];
    rinv[n] = 1.f / fmaxf((float)d, 1.f);
  }
}

// ---- f32 -> f16 copy (8 elems/thread) --------------------------------------
__global__ void k_conv16(const float* __restrict__ x, _Float16* __restrict__ y,
                         int n8) {
  int i = blockIdx.x * 256 + threadIdx.x;
  if (i >= n8) return;
  const float4* p = (const float4*)x;
  float4 a = p[2 * i], b = p[2 * i + 1];
  f16x8 o;
  o[0] = (_Float16)a.x; o[1] = (_Float16)a.y; o[2] = (_Float16)a.z; o[3] = (_Float16)a.w;
  o[4] = (_Float16)b.x; o[5] = (_Float16)b.y; o[6] = (_Float16)b.z; o[7] = (_Float16)b.w;
  ((f16x8*)y)[i] = o;
}

// ---- gather: hsum[n] = sum fwd ea16 rows (f32); hid16 = sum rev; degrev ----
__global__ __launch_bounds__(256) void k_gath_h(
    const _Float16* __restrict__ ea16, const _Float16* __restrict__ tmp16,
    const int* __restrict__ eidA, const int* __restrict__ off,
    float* __restrict__ hsum, _Float16* __restrict__ hid16,
    float* __restrict__ degrev) {
  int n = blockIdx.x * 4 + (threadIdx.x >> 6);
  if (n >= NV) return;
  int l = threadIdx.x & 63;
  float4 fs = {0.f, 0.f, 0.f, 0.f}, hv = {0.f, 0.f, 0.f, 0.f};
  int o0 = off[n], o1 = off[n + 1];
  int dr = 0;
  for (int j = o0; j < o1; j++) {
    int de = eidA[j];
    if (de < E) {
      f16x4 v = ((const f16x4*)(ea16 + (size_t)de * D))[l];
      fs.x += (float)v[0]; fs.y += (float)v[1];
      fs.z += (float)v[2]; fs.w += (float)v[3];
    } else {
      f16x4 v = ((const f16x4*)(tmp16 + (size_t)(de - E) * D))[l];
      hv.x += (float)v[0]; hv.y += (float)v[1];
      hv.z += (float)v[2]; hv.w += (float)v[3];
      dr++;
    }
  }
  ((float4*)(hsum + (size_t)n * D))[l] = fs;
  f16x4 ho;
  ho[0] = (_Float16)hv.x; ho[1] = (_Float16)hv.y;
  ho[2] = (_Float16)hv.z; ho[3] = (_Float16)hv.w;
  ((f16x4*)(hid16 + (size_t)n * D))[l] = ho;
  if (l == 0) degrev[n] = (float)dr;
}

// ---- per-layer aggregate: agg16[n] = (sum_j x16[src_j] + hsum[n])*rinv[n] --
__global__ __launch_bounds__(256) void k_agg(
    const _Float16* __restrict__ x16, const int* __restrict__ srcA,
    const int* __restrict__ off, const float* __restrict__ hsum,
    const float* __restrict__ rinv, _Float16* __restrict__ agg16) {
  int n = blockIdx.x * 4 + (threadIdx.x >> 6);
  if (n >= NV) return;
  int l = threadIdx.x & 63;
  float4 s = ((const float4*)(hsum + (size_t)n * D))[l];
  int o0 = off[n], o1 = off[n + 1];
  for (int j = o0; j < o1; j++) {
    int src = srcA[j];
    f16x4 v = ((const f16x4*)(x16 + (size_t)src * D))[l];
    s.x += (float)v[0]; s.y += (float)v[1];
    s.z += (float)v[2]; s.w += (float)v[3];
  }
  float r = rinv[n];
  f16x4 o;
  o[0] = (_Float16)(s.x * r); o[1] = (_Float16)(s.y * r);
  o[2] = (_Float16)(s.z * r); o[3] = (_Float16)(s.w * r);
  ((f16x4*)(agg16 + (size_t)n * D))[l] = o;
}

// ---- weight prep: W[K][256] f32 -> Wf [K/8][256][8] f16 --------------------
__global__ __launch_bounds__(256) void k_wprep(const float* __restrict__ W,
                                               _Float16* __restrict__ Wf) {
  __shared__ float tl[32][260];
  int tid = threadIdx.x;
  int k0 = blockIdx.x * 32;
#pragma unroll
  for (int i = 0; i < 32; i++) tl[i][tid] = W[(size_t)(k0 + i) * 256 + tid];
  __syncthreads();
  f16x8* WfV = (f16x8*)Wf;
#pragma unroll
  for (int kg = 0; kg < 4; kg++) {
    f16x8 p;
#pragma unroll
    for (int j = 0; j < 8; j++) p[j] = (_Float16)tl[kg * 8 + j][tid];
    WfV[(size_t)((k0 >> 3) + kg) * 256 + tid] = p;
  }
}

// ---- qW[n] = q @ pred_W1[:256,n] + pred_b1[n] ------------------------------
__global__ void k_qw(const float* __restrict__ q, const float* __restrict__ W1,
                     const float* __restrict__ b1, float* __restrict__ qW) {
  __shared__ float ql[D];
  int n = threadIdx.x;
  ql[n] = q[n];
  __syncthreads();
  float s = b1[n];
  for (int k = 0; k < D; k++) s += ql[k] * W1[(size_t)k * D + n];
  qW[n] = s;
}

// ---- f16 MFMA GEMM, global_load_lds 2-phase staging, N=256 per weight ------
enum AM { AF16, AF16D };
enum EP { EP_RELU16, EP_ADDC, EP_HE2, EP_PROJ2 };

// stage one 64x64 f16 K-step tile into ldsbuf (8KB), source-XOR-swizzled
template<int AMODE>
__device__ inline void stageA(const _Float16* __restrict__ A0,
                              const _Float16* __restrict__ A1,
                              int m0, int t, int tid, _Float16* ldsbuf) {
  const _Float16* src;
  int kbase;
  if (AMODE == AF16D && t >= 4) { src = A1; kbase = (t - 4) * 64; }
  else                          { src = A0; kbase = t * 64; }
  const int l  = tid & 63;
  const int w  = tid >> 6;
  const int r8 = l >> 3;                 // row within 8-row chunk
  const int kg = (l & 7) ^ r8;           // swizzled source k-group (0..7)
#pragma unroll
  for (int j = 0; j < 2; j++) {
    const int c = w * 2 + j;             // chunk 0..7 (8 rows, 1KB each)
    const int row = c * 8 + r8;
    gload16(src + (size_t)(m0 + row) * 256 + kbase + kg * 8,
            ldsbuf + c * 512);           // wave-uniform LDS base, lane*16B
  }
}

template<int AMODE, int EPI>
__global__ __launch_bounds__(256) void k_gemm(
    const _Float16* __restrict__ A0, const _Float16* __restrict__ A1,
    const float* __restrict__ addm, const float* __restrict__ rv,
    const _Float16* __restrict__ Wf, const _Float16* __restrict__ Wf2,
    const float* __restrict__ bias, const float* __restrict__ qW,
    float* __restrict__ outf, _Float16* __restrict__ o16a,
    _Float16* __restrict__ o16b, int M, int K) {
  constexpr bool DUAL = (EPI == EP_HE2 || EPI == EP_PROJ2);
  __shared__ _Float16 AS[2 * 4096];      // 16 KB double-buffered A-tile
  const int tid = threadIdx.x;
  const int w = tid >> 6;
  const int lane31 = tid & 31;
  const int hw = (tid >> 5) & 1;
  const int m0 = blockIdx.x * 64;
  const int col0 = (w << 6) + lane31;
  const int col1 = col0 + 32;

  f32x16 acc[2][2], acc2[2][2];
#pragma unroll
  for (int a = 0; a < 2; a++)
#pragma unroll
    for (int b = 0; b < 2; b++)
#pragma unroll
      for (int i = 0; i < 16; i++) { acc[a][b][i] = 0.f; acc2[a][b][i] = 0.f; }

  const f16x8* WV  = (const f16x8*)Wf;
  const f16x8* WV2 = (const f16x8*)Wf2;
  const int nt = K >> 6;
  const int sw = lane31 & 7;             // row&7 for both row frags

  stageA<AMODE>(A0, A1, m0, 0, tid, AS);
  __syncthreads();

  for (int t = 0; t < nt; ++t) {
    if (t + 1 < nt)
      stageA<AMODE>(A0, A1, m0, t + 1, tid, AS + ((t + 1) & 1) * 4096);
    const f16x8* cb = (const f16x8*)(AS + (t & 1) * 4096);
    const int k0 = t * 64;
#pragma unroll
    for (int ks = 0; ks < 4; ks++) {
      const int kgl = 2 * ks + hw;
      f16x8 a0 = cb[lane31 * 8 + (kgl ^ sw)];
      f16x8 a1 = cb[(lane31 + 32) * 8 + (kgl ^ sw)];
      size_t wi = (size_t)((k0 >> 3) + kgl) * 256;
      f16x8 b0 = WV[wi + col0];
      f16x8 b1 = WV[wi + col1];
      acc[0][0] = MFMA16(a0, b0, acc[0][0]);
      acc[0][1] = MFMA16(a0, b1, acc[0][1]);
      acc[1][0] = MFMA16(a1, b0, acc[1][0]);
      acc[1][1] = MFMA16(a1, b1, acc[1][1]);
      if (DUAL) {
        f16x8 c0 = WV2[wi + col0];
        f16x8 c1 = WV2[wi + col1];
        acc2[0][0] = MFMA16(a0, c0, acc2[0][0]);
        acc2[0][1] = MFMA16(a0, c1, acc2[0][1]);
        acc2[1][0] = MFMA16(a1, c0, acc2[1][0]);
        acc2[1][1] = MFMA16(a1, c1, acc2[1][1]);
      }
    }
    __syncthreads();
  }

  if (EPI == EP_RELU16) {
    float b0v = bias[col0], b1v = bias[col1];
#pragma unroll
    for (int rf = 0; rf < 2; rf++)
#pragma unroll
      for (int g = 0; g < 4; g++)
#pragma unroll
        for (int qq = 0; qq < 4; qq++) {
          int row = m0 + 32 * rf + qq + 8 * g + 4 * hw;
          if (row < M) {
            o16a[(size_t)row * 256 + col0] =
                (_Float16)fmaxf(acc[rf][0][4 * g + qq] + b0v, 0.f);
            o16a[(size_t)row * 256 + col1] =
                (_Float16)fmaxf(acc[rf][1][4 * g + qq] + b1v, 0.f);
          }
        }
  }
  if (EPI == EP_ADDC) {
    float b0v = bias[col0], b1v = bias[col1];
#pragma unroll
    for (int rf = 0; rf < 2; rf++)
#pragma unroll
      for (int g = 0; g < 4; g++)
#pragma unroll
        for (int qq = 0; qq < 4; qq++) {
          int row = m0 + 32 * rf + qq + 8 * g + 4 * hw;
          if (row < M) {
            float dr = rv[row];
            outf[(size_t)row * 256 + col0] =
                acc[rf][0][4 * g + qq] + addm[(size_t)row * 256 + col0] + dr * b0v;
            outf[(size_t)row * 256 + col1] =
                acc[rf][1][4 * g + qq] + addm[(size_t)row * 256 + col1] + dr * b1v;
          }
        }
  }
  if (EPI == EP_HE2) {
#pragma unroll
    for (int rf = 0; rf < 2; rf++)
#pragma unroll
      for (int g = 0; g < 4; g++)
#pragma unroll
        for (int qq = 0; qq < 4; qq++) {
          int row = m0 + 32 * rf + qq + 8 * g + 4 * hw;
          if (row < M) {
            o16a[(size_t)row * 256 + col0] = (_Float16)acc[rf][0][4 * g + qq];
            o16a[(size_t)row * 256 + col1] = (_Float16)acc[rf][1][4 * g + qq];
            o16b[(size_t)row * 256 + col0] = (_Float16)acc2[rf][0][4 * g + qq];
            o16b[(size_t)row * 256 + col1] = (_Float16)acc2[rf][1][4 * g + qq];
          }
        }
  }
  if (EPI == EP_PROJ2) {
    float b0v = bias[col0], b1v = bias[col1];
    float q0 = qW[col0], q1 = qW[col1];
#pragma unroll
    for (int rf = 0; rf < 2; rf++)
#pragma unroll
      for (int g = 0; g < 4; g++)
#pragma unroll
        for (int qq = 0; qq < 4; qq++) {
          int row = m0 + 32 * rf + qq + 8 * g + 4 * hw;
          if (row < M) {
            o16a[(size_t)row * 256 + col0] =
                (_Float16)fmaxf(acc[rf][0][4 * g + qq] + b0v, 0.f);
            o16a[(size_t)row * 256 + col1] =
                (_Float16)fmaxf(acc[rf][1][4 * g + qq] + b1v, 0.f);
            o16b[(size_t)row * 256 + col0] = (_Float16)(acc2[rf][0][4 * g + qq] + q0);
            o16b[(size_t)row * 256 + col1] = (_Float16)(acc2[rf][1][4 * g + qq] + q1);
          }
        }
  }
}

// ---- lean edge combine: logits/sampled from ea2q16 + HEh/HEt gathers -------
__global__ __launch_bounds__(256) void k_edge(
    const _Float16* __restrict__ ea2q, const _Float16* __restrict__ HEh,
    const _Float16* __restrict__ HEt, const int* __restrict__ ei32,
    const float* __restrict__ pW2, const float* __restrict__ pb2,
    const float* __restrict__ noise, float* __restrict__ dout) {
  int e = blockIdx.x * 4 + (threadIdx.x >> 6);
  int l = threadIdx.x & 63;
  int h = ei32[e], t = ei32[E + e];
  f16x4 a  = ((const f16x4*)(ea2q + (size_t)e * 256))[l];
  f16x4 hv = ((const f16x4*)(HEh + (size_t)h * 256))[l];
  f16x4 tv = ((const f16x4*)(HEt + (size_t)t * 256))[l];
  float4 wv = ((const float4*)pW2)[l];
  float s = fmaxf((float)a[0] + (float)hv[0] + (float)tv[0], 0.f) * wv.x
          + fmaxf((float)a[1] + (float)hv[1] + (float)tv[1], 0.f) * wv.y
          + fmaxf((float)a[2] + (float)hv[2] + (float)tv[2], 0.f) * wv.z
          + fmaxf((float)a[3] + (float)hv[3] + (float)tv[3], 0.f) * wv.w;
#pragma unroll
  for (int m = 1; m <= 32; m <<= 1) s += __shfl_xor(s, m);
  if (l == 0) {
    float lg = s + pb2[0];
    float nz = noise[e];
    float rn = logf(nz) - logf(1.f - nz);
    dout[e] = lg;
    dout[E + e] = 1.f / (1.f + expf(-(lg + rn)));
  }
}

extern "C" void kernel_launch(void* const* d_in, const int* in_sizes, int n_in,
                              void* d_out, int out_size, void* d_ws, size_t ws_size,
                              hipStream_t stream) {
  const float* entity = (const float*)d_in[0];
  const float* ea     = (const float*)d_in[1];
  const float* q      = (const float*)d_in[2];
  const float* noise  = (const float*)d_in[3];
  const float* W_pr1  = (const float*)d_in[4];
  const float* b_pr1  = (const float*)d_in[5];
  const float* W_pr2  = (const float*)d_in[6];
  const float* b_pr2  = (const float*)d_in[7];
  const float* sW0    = (const float*)d_in[8];
  const float* sb0    = (const float*)d_in[9];
  const float* sW1    = (const float*)d_in[10];
  const float* sb1    = (const float*)d_in[11];
  const float* pW1    = (const float*)d_in[12];
  const float* pb1    = (const float*)d_in[13];
  const float* pW2    = (const float*)d_in[14];
  const float* pb2    = (const float*)d_in[15];
  const void*  ei_raw = d_in[16];

  char* ws = (char*)d_ws;
  const size_t EDH = (size_t)E * D * 2;    // 102.4 MB f16 edge matrix
  const size_t NDB = (size_t)NV * D * 4;   // 51.2 MB f32 node matrix
  const size_t NDH = (size_t)NV * D * 2;   // 25.6 MB f16 node matrix
  const size_t PAD = 64 * 256 * 2;         // OOB tile-read slack (32 KB)
  size_t off_b = 0;
  char* r0  = ws + off_b; off_b += EDH + PAD;        // ea16
  char* r1a = ws + off_b; off_b += EDH + PAD;        // tmp16
  char* r1b = ws + off_b; off_b += EDH + PAD;        // ea2q16
  char* r2  = ws + off_b; off_b += NDB + PAD;        // hsum f32 -> HEh16|HEt16
  char* r3  = ws + off_b; off_b += NDH + PAD;        // hid16 -> agg16
  char* r4  = ws + off_b; off_b += NDH + PAD;        // ent16 -> out116
  char* r5  = ws + off_b; off_b += NDH + PAD;        // out016
  auto alloc_w = [&](int K) { _Float16* p = (_Float16*)(ws + off_b);
                              off_b += (size_t)K * 256 * 2; return p; };
  _Float16* Wpr1f = alloc_w(256);
  _Float16* Wpr2f = alloc_w(256);
  _Float16* sW0f  = alloc_w(512);
  _Float16* sW1f  = alloc_w(512);
  _Float16* Whehf = alloc_w(512);
  _Float16* Whetf = alloc_w(512);
  _Float16* Weaf  = alloc_w(256);
  float* rinv   = (float*)(ws + off_b); off_b += (size_t)NV * 4;
  float* degrev = (float*)(ws + off_b); off_b += (size_t)NV * 4;
  float* qW     = (float*)(ws + off_b); off_b += 1024;
  int*   ei32   = (int*)(ws + off_b);   off_b += (size_t)TWOE * 4;
  int*   eidA   = (int*)(ws + off_b);   off_b += (size_t)TWOE * 4;
  int*   srcA   = (int*)(ws + off_b);   off_b += (size_t)TWOE * 4;
  int*   offA   = (int*)(ws + off_b);   off_b += (size_t)(NV + 1) * 4;
  int*   deg    = (int*)(ws + off_b);   off_b += (size_t)NV * 4;
  int*   cursor = (int*)(ws + off_b);   off_b += (size_t)NV * 4;
  int*   flag   = (int*)(ws + off_b);   off_b += 64;

  // lifetime aliases
  _Float16* ea16   = (_Float16*)r0;          // conv -> PROJ2/gath_h
  _Float16* tmp16  = (_Float16*)r1a;         // PROJ2 -> gath_h
  _Float16* ea2q16 = (_Float16*)r1b;         // PROJ2 -> k_edge
  float*    hsum   = (float*)r2;             // gath -> ADDC -> agg0/agg1
  _Float16* HEh16  = (_Float16*)r2;          // HE2 -> k_edge
  _Float16* HEt16  = (_Float16*)(r2 + NDH);
  _Float16* hid16  = (_Float16*)r3;          // gath -> ADDC
  _Float16* agg16  = (_Float16*)r3;          // agg -> sage (per layer)
  _Float16* ent16  = (_Float16*)r4;          // conv -> agg0/sage0
  _Float16* out116 = (_Float16*)r4;          // sage1 -> HE2
  _Float16* out016 = (_Float16*)r5;          // sage0 -> agg1/sage1/HE2

  // ---- indices & CSR ----
  k_detect<<<1, 256, 0, stream>>>(ei_raw, flag);
  k_convert<<<(TWOE + 255) / 256, 256, 0, stream>>>(ei_raw, flag, ei32);
  hipMemsetAsync(deg, 0, (size_t)NV * 4, stream);
  hipMemsetAsync(cursor, 0, (size_t)NV * 4, stream);
  k_deg<<<(TWOE + 255) / 256, 256, 0, stream>>>(ei32, deg);
  k_scan<<<1, 1024, 0, stream>>>(deg, offA);
  k_fill<<<(TWOE + 255) / 256, 256, 0, stream>>>(ei32, offA, cursor, eidA, srcA);
  k_rinv<<<(NV + 255) / 256, 256, 0, stream>>>(offA, rinv);

  // ---- weight prep + f16 shadows ----
  k_wprep<<<256 / 32, 256, 0, stream>>>(W_pr1, Wpr1f);
  k_wprep<<<256 / 32, 256, 0, stream>>>(W_pr2, Wpr2f);
  k_wprep<<<512 / 32, 256, 0, stream>>>(sW0, sW0f);
  k_wprep<<<512 / 32, 256, 0, stream>>>(sW1, sW1f);
  k_wprep<<<512 / 32, 256, 0, stream>>>(pW1 + 256 * 256, Whehf);
  k_wprep<<<512 / 32, 256, 0, stream>>>(pW1 + 1024 * 256, Whetf);
  k_wprep<<<256 / 32, 256, 0, stream>>>(pW1 + 768 * 256, Weaf);
  k_conv16<<<(NV * D / 8 + 255) / 256, 256, 0, stream>>>(entity, ent16, NV * D / 8);
  k_conv16<<<(E * D / 8 + 255) / 256, 256, 0, stream>>>(ea, ea16, E * D / 8);
  k_qw<<<1, 256, 0, stream>>>(q, pW1, pb1, qW);

  // ---- fused proj+EA2: tmp16 = relu(ea@Wpr1+b1); ea2q16 = ea@Wea + qW ----
  k_gemm<AF16, EP_PROJ2><<<E / 64, 256, 0, stream>>>(
      ea16, nullptr, nullptr, nullptr, Wpr1f, Weaf, b_pr1, qW,
      nullptr, tmp16, ea2q16, E, 256);
  // gather: hsum = sum_fwd ea16 (f32); hid16 = sum_rev tmp16; degrev
  k_gath_h<<<(NV + 3) / 4, 256, 0, stream>>>(ea16, tmp16, eidA, offA, hsum, hid16, degrev);
  // hsum += hid16 @ Wpr2 + degrev*b_pr2   (in place)
  k_gemm<AF16, EP_ADDC><<<(NV + 63) / 64, 256, 0, stream>>>(
      hid16, nullptr, hsum, degrev, Wpr2f, nullptr, b_pr2, nullptr,
      hsum, nullptr, nullptr, NV, 256);

  // ---- layer 0 ----
  k_agg<<<(NV + 3) / 4, 256, 0, stream>>>(ent16, srcA, offA, hsum, rinv, agg16);
  k_gemm<AF16D, EP_RELU16><<<(NV + 63) / 64, 256, 0, stream>>>(
      ent16, agg16, nullptr, nullptr, sW0f, nullptr, sb0, nullptr,
      nullptr, out016, nullptr, NV, 512);
  // ---- layer 1 ----
  k_agg<<<(NV + 3) / 4, 256, 0, stream>>>(out016, srcA, offA, hsum, rinv, agg16);
  k_gemm<AF16D, EP_RELU16><<<(NV + 63) / 64, 256, 0, stream>>>(
      out016, agg16, nullptr, nullptr, sW1f, nullptr, sb1, nullptr,
      nullptr, out116, nullptr, NV, 512);

  // ---- HE dual-weight GEMM: HEh16/HEt16 (into hsum region; hsum dead) ----
  k_gemm<AF16D, EP_HE2><<<(NV + 63) / 64, 256, 0, stream>>>(
      out016, out116, nullptr, nullptr, Whehf, Whetf, nullptr, nullptr,
      nullptr, HEh16, HEt16, NV, 512);

  // ---- lean edge combine ----
  k_edge<<<E / 4, 256, 0, stream>>>(ea2q16, HEh16, HEt16, ei32, pW2, pb2, noise,
                                    (float*)d_out);
}

// Round 9
// 734.262 us; speedup vs baseline: 1.3199x; 1.1502x over previous
//
#include <hip/hip_runtime.h>
#include <math.h>

// FineGrainedRetriever round 9: fix the vmcnt-FIFO hazard in k_gemm. Per K-step:
// (1) preload ALL W-fragments of the step into registers (older VMEM), then
// (2) issue next tile's global_load_lds staging (younger -> never waited on by
// W consumption), then (3) MFMA burst, then barrier (staging already arrived).
// sched_barrier(0) pins the issue order. launch_bounds: dual kernels 2 waves/EU
// (256 VGPR budget), single 4 waves/EU. Everything else as round 8.

namespace {
constexpr int E    = 200000;
constexpr int NV   = 50000;
constexpr int D    = 256;
constexpr int TWOE = 2 * E;
}

typedef __attribute__((ext_vector_type(8))) _Float16 f16x8;
typedef __attribute__((ext_vector_type(4))) _Float16 f16x4;
typedef __attribute__((ext_vector_type(16))) float f32x16;

#define MFMA16(a, b, c) __builtin_amdgcn_mfma_f32_32x32x16_f16((a), (b), (c), 0, 0, 0)

typedef const __attribute__((address_space(1))) void* gas_t;
typedef __attribute__((address_space(3))) void* las_t;

__device__ inline void gload16(const void* g, void* l) {
  __builtin_amdgcn_global_load_lds((gas_t)g, (las_t)l, 16, 0, 0);
}

// ---- edge_index dtype probe (int64 vs int32) -------------------------------
__global__ void k_detect(const void* ei_raw, int* flag) {
  __shared__ int bad;
  if (threadIdx.x == 0) bad = 0;
  __syncthreads();
  const long long* p = (const long long*)ei_raw;
  long long v = p[threadIdx.x];
  if (v < 0 || v >= (long long)NV) atomicOr(&bad, 1);
  __syncthreads();
  if (threadIdx.x == 0) *flag = bad ? 0 : 1;  // 1 => int64
}

__global__ void k_convert(const void* ei_raw, const int* __restrict__ flag,
                          int* __restrict__ ei32) {
  int i = blockIdx.x * 256 + threadIdx.x;
  if (i >= TWOE) return;
  if (*flag) ei32[i] = (int)((const long long*)ei_raw)[i];
  else       ei32[i] = ((const int*)ei_raw)[i];
}

// ---- CSR build -------------------------------------------------------------
__global__ void k_deg(const int* __restrict__ ei32, int* __restrict__ deg) {
  int de = blockIdx.x * 256 + threadIdx.x;
  if (de >= TWOE) return;
  int dst = (de < E) ? ei32[E + de] : ei32[de - E];
  atomicAdd(&deg[dst], 1);
}

__global__ __launch_bounds__(1024) void k_scan(const int* __restrict__ deg,
                                               int* __restrict__ off) {
  __shared__ int wsum[16];
  __shared__ int carryS;
  int tid = threadIdx.x;
  int lane = tid & 63, wv = tid >> 6;
  if (tid == 0) carryS = 0;
  __syncthreads();
  for (int base = 0; base < NV; base += 1024) {
    int i = base + tid;
    int v = (i < NV) ? deg[i] : 0;
    int s = v;
#pragma unroll
    for (int d = 1; d < 64; d <<= 1) {
      int t = __shfl_up(s, d);
      if (lane >= d) s += t;
    }
    if (lane == 63) wsum[wv] = s;
    int carry = carryS;
    __syncthreads();
    if (wv == 0) {
      int ws = (lane < 16) ? wsum[lane] : 0;
#pragma unroll
      for (int d = 1; d < 16; d <<= 1) {
        int t = __shfl_up(ws, d);
        if (lane >= d) ws += t;
      }
      if (lane < 16) wsum[lane] = ws;
    }
    __syncthreads();
    int wexcl = (wv == 0) ? 0 : wsum[wv - 1];
    if (i < NV) off[i] = carry + wexcl + s - v;
    if (tid == 1023) carryS = carry + wsum[15];
    __syncthreads();
  }
  if (tid == 0) off[NV] = carryS;
}

__global__ void k_fill(const int* __restrict__ ei32, const int* __restrict__ off,
                       int* __restrict__ cursor, int* __restrict__ eidA,
                       int* __restrict__ srcA) {
  int de = blockIdx.x * 256 + threadIdx.x;
  if (de >= TWOE) return;
  int dst = (de < E) ? ei32[E + de] : ei32[de - E];
  int p = atomicAdd(&cursor[dst], 1);
  int idx = off[dst] + p;
  eidA[idx] = de;
  srcA[idx] = ei32[de];
}

__global__ void k_rinv(const int* __restrict__ off, float* __restrict__ rinv) {
  int n = blockIdx.x * 256 + threadIdx.x;
  if (n < NV) {
    int d = off[n + 1] - off[n];
    rinv[n] = 1.f / fmaxf((float)d, 1.f);
  }
}

// ---- f32 -> f16 copy (8 elems/thread) --------------------------------------
__global__ void k_conv16(const float* __restrict__ x, _Float16* __restrict__ y,
                         int n8) {
  int i = blockIdx.x * 256 + threadIdx.x;
  if (i >= n8) return;
  const float4* p = (const float4*)x;
  float4 a = p[2 * i], b = p[2 * i + 1];
  f16x8 o;
  o[0] = (_Float16)a.x; o[1] = (_Float16)a.y; o[2] = (_Float16)a.z; o[3] = (_Float16)a.w;
  o[4] = (_Float16)b.x; o[5] = (_Float16)b.y; o[6] = (_Float16)b.z; o[7] = (_Float16)b.w;
  ((f16x8*)y)[i] = o;
}

// ---- gather: hsum[n] = sum fwd ea16 rows (f32); hid16 = sum rev; degrev ----
__global__ __launch_bounds__(256) void k_gath_h(
    const _Float16* __restrict__ ea16, const _Float16* __restrict__ tmp16,
    const int* __restrict__ eidA, const int* __restrict__ off,
    float* __restrict__ hsum, _Float16* __restrict__ hid16,
    float* __restrict__ degrev) {
  int n = blockIdx.x * 4 + (threadIdx.x >> 6);
  if (n >= NV) return;
  int l = threadIdx.x & 63;
  float4 fs = {0.f, 0.f, 0.f, 0.f}, hv = {0.f, 0.f, 0.f, 0.f};
  int o0 = off[n], o1 = off[n + 1];
  int dr = 0;
  for (int j = o0; j < o1; j++) {
    int de = eidA[j];
    if (de < E) {
      f16x4 v = ((const f16x4*)(ea16 + (size_t)de * D))[l];
      fs.x += (float)v[0]; fs.y += (float)v[1];
      fs.z += (float)v[2]; fs.w += (float)v[3];
    } else {
      f16x4 v = ((const f16x4*)(tmp16 + (size_t)(de - E) * D))[l];
      hv.x += (float)v[0]; hv.y += (float)v[1];
      hv.z += (float)v[2]; hv.w += (float)v[3];
      dr++;
    }
  }
  ((float4*)(hsum + (size_t)n * D))[l] = fs;
  f16x4 ho;
  ho[0] = (_Float16)hv.x; ho[1] = (_Float16)hv.y;
  ho[2] = (_Float16)hv.z; ho[3] = (_Float16)hv.w;
  ((f16x4*)(hid16 + (size_t)n * D))[l] = ho;
  if (l == 0) degrev[n] = (float)dr;
}

// ---- per-layer aggregate: agg16[n] = (sum_j x16[src_j] + hsum[n])*rinv[n] --
__global__ __launch_bounds__(256) void k_agg(
    const _Float16* __restrict__ x16, const int* __restrict__ srcA,
    const int* __restrict__ off, const float* __restrict__ hsum,
    const float* __restrict__ rinv, _Float16* __restrict__ agg16) {
  int n = blockIdx.x * 4 + (threadIdx.x >> 6);
  if (n >= NV) return;
  int l = threadIdx.x & 63;
  float4 s = ((const float4*)(hsum + (size_t)n * D))[l];
  int o0 = off[n], o1 = off[n + 1];
  for (int j = o0; j < o1; j++) {
    int src = srcA[j];
    f16x4 v = ((const f16x4*)(x16 + (size_t)src * D))[l];
    s.x += (float)v[0]; s.y += (float)v[1];
    s.z += (float)v[2]; s.w += (float)v[3];
  }
  float r = rinv[n];
  f16x4 o;
  o[0] = (_Float16)(s.x * r); o[1] = (_Float16)(s.y * r);
  o[2] = (_Float16)(s.z * r); o[3] = (_Float16)(s.w * r);
  ((f16x4*)(agg16 + (size_t)n * D))[l] = o;
}

// ---- weight prep: W[K][256] f32 -> Wf [K/8][256][8] f16 --------------------
__global__ __launch_bounds__(256) void k_wprep(const float* __restrict__ W,
                                               _Float16* __restrict__ Wf) {
  __shared__ float tl[32][260];
  int tid = threadIdx.x;
  int k0 = blockIdx.x * 32;
#pragma unroll
  for (int i = 0; i < 32; i++) tl[i][tid] = W[(size_t)(k0 + i) * 256 + tid];
  __syncthreads();
  f16x8* WfV = (f16x8*)Wf;
#pragma unroll
  for (int kg = 0; kg < 4; kg++) {
    f16x8 p;
#pragma unroll
    for (int j = 0; j < 8; j++) p[j] = (_Float16)tl[kg * 8 + j][tid];
    WfV[(size_t)((k0 >> 3) + kg) * 256 + tid] = p;
  }
}

// ---- qW[n] = q @ pred_W1[:256,n] + pred_b1[n] ------------------------------
__global__ void k_qw(const float* __restrict__ q, const float* __restrict__ W1,
                     const float* __restrict__ b1, float* __restrict__ qW) {
  __shared__ float ql[D];
  int n = threadIdx.x;
  ql[n] = q[n];
  __syncthreads();
  float s = b1[n];
  for (int k = 0; k < D; k++) s += ql[k] * W1[(size_t)k * D + n];
  qW[n] = s;
}

// ---- f16 MFMA GEMM, gload_lds staging, W-preload-first ordering ------------
enum AM { AF16, AF16D };
enum EP { EP_RELU16, EP_ADDC, EP_HE2, EP_PROJ2 };

// stage one 64x64 f16 K-step tile into ldsbuf (8KB), source-XOR-swizzled
template<int AMODE>
__device__ inline void stageA(const _Float16* __restrict__ A0,
                              const _Float16* __restrict__ A1,
                              int m0, int t, int tid, _Float16* ldsbuf) {
  const _Float16* src;
  int kbase;
  if (AMODE == AF16D && t >= 4) { src = A1; kbase = (t - 4) * 64; }
  else                          { src = A0; kbase = t * 64; }
  const int l  = tid & 63;
  const int w  = tid >> 6;
  const int r8 = l >> 3;                 // row within 8-row chunk
  const int kg = (l & 7) ^ r8;           // swizzled source k-group (0..7)
#pragma unroll
  for (int j = 0; j < 2; j++) {
    const int c = w * 2 + j;             // chunk 0..7 (8 rows, 1KB each)
    const int row = c * 8 + r8;
    gload16(src + (size_t)(m0 + row) * 256 + kbase + kg * 8,
            ldsbuf + c * 512);           // wave-uniform LDS base, lane*16B
  }
}

template<int AMODE, int EPI>
__global__ __launch_bounds__(256, ((EPI == EP_HE2 || EPI == EP_PROJ2) ? 2 : 4))
void k_gemm(
    const _Float16* __restrict__ A0, const _Float16* __restrict__ A1,
    const float* __restrict__ addm, const float* __restrict__ rv,
    const _Float16* __restrict__ Wf, const _Float16* __restrict__ Wf2,
    const float* __restrict__ bias, const float* __restrict__ qW,
    float* __restrict__ outf, _Float16* __restrict__ o16a,
    _Float16* __restrict__ o16b, int M, int K) {
  constexpr bool DUAL = (EPI == EP_HE2 || EPI == EP_PROJ2);
  __shared__ _Float16 AS[2 * 4096];      // 16 KB double-buffered A-tile
  const int tid = threadIdx.x;
  const int w = tid >> 6;
  const int lane31 = tid & 31;
  const int hw = (tid >> 5) & 1;
  const int m0 = blockIdx.x * 64;
  const int col0 = (w << 6) + lane31;
  const int col1 = col0 + 32;

  f32x16 acc[2][2], acc2[2][2];
#pragma unroll
  for (int a = 0; a < 2; a++)
#pragma unroll
    for (int b = 0; b < 2; b++)
#pragma unroll
      for (int i = 0; i < 16; i++) { acc[a][b][i] = 0.f; acc2[a][b][i] = 0.f; }

  const f16x8* WV  = (const f16x8*)Wf;
  const f16x8* WV2 = (const f16x8*)Wf2;
  const int nt = K >> 6;
  const int sw = lane31 & 7;             // row&7 for both row frags

  stageA<AMODE>(A0, A1, m0, 0, tid, AS);
  __syncthreads();

  for (int t = 0; t < nt; ++t) {
    const int k0 = t * 64;
    // (1) preload ALL W-frags of this step FIRST (oldest VMEM -> counted waits
    //     on these never drain the staging loads issued below)
    f16x8 wb0[4], wb1[4], wc0[4], wc1[4];
#pragma unroll
    for (int ks = 0; ks < 4; ks++) {
      const int kgl = 2 * ks + hw;
      size_t wi = (size_t)((k0 >> 3) + kgl) * 256;
      wb0[ks] = WV[wi + col0];
      wb1[ks] = WV[wi + col1];
      if (DUAL) { wc0[ks] = WV2[wi + col0]; wc1[ks] = WV2[wi + col1]; }
    }
    __builtin_amdgcn_sched_barrier(0);
    // (2) issue next tile's staging (younger; drains only at step-end barrier,
    //     fully overlapped with the MFMA burst below)
    if (t + 1 < nt)
      stageA<AMODE>(A0, A1, m0, t + 1, tid, AS + ((t + 1) & 1) * 4096);
    __builtin_amdgcn_sched_barrier(0);
    // (3) MFMA burst on current buffer
    const f16x8* cb = (const f16x8*)(AS + (t & 1) * 4096);
#pragma unroll
    for (int ks = 0; ks < 4; ks++) {
      const int kgl = 2 * ks + hw;
      f16x8 a0 = cb[lane31 * 8 + (kgl ^ sw)];
      f16x8 a1 = cb[(lane31 + 32) * 8 + (kgl ^ sw)];
      acc[0][0] = MFMA16(a0, wb0[ks], acc[0][0]);
      acc[0][1] = MFMA16(a0, wb1[ks], acc[0][1]);
      acc[1][0] = MFMA16(a1, wb0[ks], acc[1][0]);
      acc[1][1] = MFMA16(a1, wb1[ks], acc[1][1]);
      if (DUAL) {
        acc2[0][0] = MFMA16(a0, wc0[ks], acc2[0][0]);
        acc2[0][1] = MFMA16(a0, wc1[ks], acc2[0][1]);
        acc2[1][0] = MFMA16(a1, wc0[ks], acc2[1][0]);
        acc2[1][1] = MFMA16(a1, wc1[ks], acc2[1][1]);
      }
    }
    __syncthreads();
  }

  if (EPI == EP_RELU16) {
    float b0v = bias[col0], b1v = bias[col1];
#pragma unroll
    for (int rf = 0; rf < 2; rf++)
#pragma unroll
      for (int g = 0; g < 4; g++)
#pragma unroll
        for (int qq = 0; qq < 4; qq++) {
          int row = m0 + 32 * rf + qq + 8 * g + 4 * hw;
          if (row < M) {
            o16a[(size_t)row * 256 + col0] =
                (_Float16)fmaxf(acc[rf][0][4 * g + qq] + b0v, 0.f);
            o16a[(size_t)row * 256 + col1] =
                (_Float16)fmaxf(acc[rf][1][4 * g + qq] + b1v, 0.f);
          }
        }
  }
  if (EPI == EP_ADDC) {
    float b0v = bias[col0], b1v = bias[col1];
#pragma unroll
    for (int rf = 0; rf < 2; rf++)
#pragma unroll
      for (int g = 0; g < 4; g++)
#pragma unroll
        for (int qq = 0; qq < 4; qq++) {
          int row = m0 + 32 * rf + qq + 8 * g + 4 * hw;
          if (row < M) {
            float dr = rv[row];
            outf[(size_t)row * 256 + col0] =
                acc[rf][0][4 * g + qq] + addm[(size_t)row * 256 + col0] + dr * b0v;
            outf[(size_t)row * 256 + col1] =
                acc[rf][1][4 * g + qq] + addm[(size_t)row * 256 + col1] + dr * b1v;
          }
        }
  }
  if (EPI == EP_HE2) {
#pragma unroll
    for (int rf = 0; rf < 2; rf++)
#pragma unroll
      for (int g = 0; g < 4; g++)
#pragma unroll
        for (int qq = 0; qq < 4; qq++) {
          int row = m0 + 32 * rf + qq + 8 * g + 4 * hw;
          if (row < M) {
            o16a[(size_t)row * 256 + col0] = (_Float16)acc[rf][0][4 * g + qq];
            o16a[(size_t)row * 256 + col1] = (_Float16)acc[rf][1][4 * g + qq];
            o16b[(size_t)row * 256 + col0] = (_Float16)acc2[rf][0][4 * g + qq];
            o16b[(size_t)row * 256 + col1] = (_Float16)acc2[rf][1][4 * g + qq];
          }
        }
  }
  if (EPI == EP_PROJ2) {
    float b0v = bias[col0], b1v = bias[col1];
    float q0 = qW[col0], q1 = qW[col1];
#pragma unroll
    for (int rf = 0; rf < 2; rf++)
#pragma unroll
      for (int g = 0; g < 4; g++)
#pragma unroll
        for (int qq = 0; qq < 4; qq++) {
          int row = m0 + 32 * rf + qq + 8 * g + 4 * hw;
          if (row < M) {
            o16a[(size_t)row * 256 + col0] =
                (_Float16)fmaxf(acc[rf][0][4 * g + qq] + b0v, 0.f);
            o16a[(size_t)row * 256 + col1] =
                (_Float16)fmaxf(acc[rf][1][4 * g + qq] + b1v, 0.f);
            o16b[(size_t)row * 256 + col0] = (_Float16)(acc2[rf][0][4 * g + qq] + q0);
            o16b[(size_t)row * 256 + col1] = (_Float16)(acc2[rf][1][4 * g + qq] + q1);
          }
        }
  }
}

// ---- lean edge combine: logits/sampled from ea2q16 + HEh/HEt gathers -------
__global__ __launch_bounds__(256) void k_edge(
    const _Float16* __restrict__ ea2q, const _Float16* __restrict__ HEh,
    const _Float16* __restrict__ HEt, const int* __restrict__ ei32,
    const float* __restrict__ pW2, const float* __restrict__ pb2,
    const float* __restrict__ noise, float* __restrict__ dout) {
  int e = blockIdx.x * 4 + (threadIdx.x >> 6);
  int l = threadIdx.x & 63;
  int h = ei32[e], t = ei32[E + e];
  f16x4 a  = ((const f16x4*)(ea2q + (size_t)e * 256))[l];
  f16x4 hv = ((const f16x4*)(HEh + (size_t)h * 256))[l];
  f16x4 tv = ((const f16x4*)(HEt + (size_t)t * 256))[l];
  float4 wv = ((const float4*)pW2)[l];
  float s = fmaxf((float)a[0] + (float)hv[0] + (float)tv[0], 0.f) * wv.x
          + fmaxf((float)a[1] + (float)hv[1] + (float)tv[1], 0.f) * wv.y
          + fmaxf((float)a[2] + (float)hv[2] + (float)tv[2], 0.f) * wv.z
          + fmaxf((float)a[3] + (float)hv[3] + (float)tv[3], 0.f) * wv.w;
#pragma unroll
  for (int m = 1; m <= 32; m <<= 1) s += __shfl_xor(s, m);
  if (l == 0) {
    float lg = s + pb2[0];
    float nz = noise[e];
    float rn = logf(nz) - logf(1.f - nz);
    dout[e] = lg;
    dout[E + e] = 1.f / (1.f + expf(-(lg + rn)));
  }
}

extern "C" void kernel_launch(void* const* d_in, const int* in_sizes, int n_in,
                              void* d_out, int out_size, void* d_ws, size_t ws_size,
                              hipStream_t stream) {
  const float* entity = (const float*)d_in[0];
  const float* ea     = (const float*)d_in[1];
  const float* q      = (const float*)d_in[2];
  const float* noise  = (const float*)d_in[3];
  const float* W_pr1  = (const float*)d_in[4];
  const float* b_pr1  = (const float*)d_in[5];
  const float* W_pr2  = (const float*)d_in[6];
  const float* b_pr2  = (const float*)d_in[7];
  const float* sW0    = (const float*)d_in[8];
  const float* sb0    = (const float*)d_in[9];
  const float* sW1    = (const float*)d_in[10];
  const float* sb1    = (const float*)d_in[11];
  const float* pW1    = (const float*)d_in[12];
  const float* pb1    = (const float*)d_in[13];
  const float* pW2    = (const float*)d_in[14];
  const float* pb2    = (const float*)d_in[15];
  const void*  ei_raw = d_in[16];

  char* ws = (char*)d_ws;
  const size_t EDH = (size_t)E * D * 2;    // 102.4 MB f16 edge matrix
  const size_t NDB = (size_t)NV * D * 4;   // 51.2 MB f32 node matrix
  const size_t NDH = (size_t)NV * D * 2;   // 25.6 MB f16 node matrix
  const size_t PAD = 64 * 256 * 2;         // OOB tile-read slack (32 KB)
  size_t off_b = 0;
  char* r0  = ws + off_b; off_b += EDH + PAD;        // ea16
  char* r1a = ws + off_b; off_b += EDH + PAD;        // tmp16
  char* r1b = ws + off_b; off_b += EDH + PAD;        // ea2q16
  char* r2  = ws + off_b; off_b += NDB + PAD;        // hsum f32 -> HEh16|HEt16
  char* r3  = ws + off_b; off_b += NDH + PAD;        // hid16 -> agg16
  char* r4  = ws + off_b; off_b += NDH + PAD;        // ent16 -> out116
  char* r5  = ws + off_b; off_b += NDH + PAD;        // out016
  auto alloc_w = [&](int K) { _Float16* p = (_Float16*)(ws + off_b);
                              off_b += (size_t)K * 256 * 2; return p; };
  _Float16* Wpr1f = alloc_w(256);
  _Float16* Wpr2f = alloc_w(256);
  _Float16* sW0f  = alloc_w(512);
  _Float16* sW1f  = alloc_w(512);
  _Float16* Whehf = alloc_w(512);
  _Float16* Whetf = alloc_w(512);
  _Float16* Weaf  = alloc_w(256);
  float* rinv   = (float*)(ws + off_b); off_b += (size_t)NV * 4;
  float* degrev = (float*)(ws + off_b); off_b += (size_t)NV * 4;
  float* qW     = (float*)(ws + off_b); off_b += 1024;
  int*   ei32   = (int*)(ws + off_b);   off_b += (size_t)TWOE * 4;
  int*   eidA   = (int*)(ws + off_b);   off_b += (size_t)TWOE * 4;
  int*   srcA   = (int*)(ws + off_b);   off_b += (size_t)TWOE * 4;
  int*   offA   = (int*)(ws + off_b);   off_b += (size_t)(NV + 1) * 4;
  int*   deg    = (int*)(ws + off_b);   off_b += (size_t)NV * 4;
  int*   cursor = (int*)(ws + off_b);   off_b += (size_t)NV * 4;
  int*   flag   = (int*)(ws + off_b);   off_b += 64;

  // lifetime aliases
  _Float16* ea16   = (_Float16*)r0;          // conv -> PROJ2/gath_h
  _Float16* tmp16  = (_Float16*)r1a;         // PROJ2 -> gath_h
  _Float16* ea2q16 = (_Float16*)r1b;         // PROJ2 -> k_edge
  float*    hsum   = (float*)r2;             // gath -> ADDC -> agg0/agg1
  _Float16* HEh16  = (_Float16*)r2;          // HE2 -> k_edge
  _Float16* HEt16  = (_Float16*)(r2 + NDH);
  _Float16* hid16  = (_Float16*)r3;          // gath -> ADDC
  _Float16* agg16  = (_Float16*)r3;          // agg -> sage (per layer)
  _Float16* ent16  = (_Float16*)r4;          // conv -> agg0/sage0
  _Float16* out116 = (_Float16*)r4;          // sage1 -> HE2
  _Float16* out016 = (_Float16*)r5;          // sage0 -> agg1/sage1/HE2

  // ---- indices & CSR ----
  k_detect<<<1, 256, 0, stream>>>(ei_raw, flag);
  k_convert<<<(TWOE + 255) / 256, 256, 0, stream>>>(ei_raw, flag, ei32);
  hipMemsetAsync(deg, 0, (size_t)NV * 4, stream);
  hipMemsetAsync(cursor, 0, (size_t)NV * 4, stream);
  k_deg<<<(TWOE + 255) / 256, 256, 0, stream>>>(ei32, deg);
  k_scan<<<1, 1024, 0, stream>>>(deg, offA);
  k_fill<<<(TWOE + 255) / 256, 256, 0, stream>>>(ei32, offA, cursor, eidA, srcA);
  k_rinv<<<(NV + 255) / 256, 256, 0, stream>>>(offA, rinv);

  // ---- weight prep + f16 shadows ----
  k_wprep<<<256 / 32, 256, 0, stream>>>(W_pr1, Wpr1f);
  k_wprep<<<256 / 32, 256, 0, stream>>>(W_pr2, Wpr2f);
  k_wprep<<<512 / 32, 256, 0, stream>>>(sW0, sW0f);
  k_wprep<<<512 / 32, 256, 0, stream>>>(sW1, sW1f);
  k_wprep<<<512 / 32, 256, 0, stream>>>(pW1 + 256 * 256, Whehf);
  k_wprep<<<512 / 32, 256, 0, stream>>>(pW1 + 1024 * 256, Whetf);
  k_wprep<<<256 / 32, 256, 0, stream>>>(pW1 + 768 * 256, Weaf);
  k_conv16<<<(NV * D / 8 + 255) / 256, 256, 0, stream>>>(entity, ent16, NV * D / 8);
  k_conv16<<<(E * D / 8 + 255) / 256, 256, 0, stream>>>(ea, ea16, E * D / 8);
  k_qw<<<1, 256, 0, stream>>>(q, pW1, pb1, qW);

  // ---- fused proj+EA2: tmp16 = relu(ea@Wpr1+b1); ea2q16 = ea@Wea + qW ----
  k_gemm<AF16, EP_PROJ2><<<E / 64, 256, 0, stream>>>(
      ea16, nullptr, nullptr, nullptr, Wpr1f, Weaf, b_pr1, qW,
      nullptr, tmp16, ea2q16, E, 256);
  // gather: hsum = sum_fwd ea16 (f32); hid16 = sum_rev tmp16; degrev
  k_gath_h<<<(NV + 3) / 4, 256, 0, stream>>>(ea16, tmp16, eidA, offA, hsum, hid16, degrev);
  // hsum += hid16 @ Wpr2 + degrev*b_pr2   (in place)
  k_gemm<AF16, EP_ADDC><<<(NV + 63) / 64, 256, 0, stream>>>(
      hid16, nullptr, hsum, degrev, Wpr2f, nullptr, b_pr2, nullptr,
      hsum, nullptr, nullptr, NV, 256);

  // ---- layer 0 ----
  k_agg<<<(NV + 3) / 4, 256, 0, stream>>>(ent16, srcA, offA, hsum, rinv, agg16);
  k_gemm<AF16D, EP_RELU16><<<(NV + 63) / 64, 256, 0, stream>>>(
      ent16, agg16, nullptr, nullptr, sW0f, nullptr, sb0, nullptr,
      nullptr, out016, nullptr, NV, 512);
  // ---- layer 1 ----
  k_agg<<<(NV + 3) / 4, 256, 0, stream>>>(out016, srcA, offA, hsum, rinv, agg16);
  k_gemm<AF16D, EP_RELU16><<<(NV + 63) / 64, 256, 0, stream>>>(
      out016, agg16, nullptr, nullptr, sW1f, nullptr, sb1, nullptr,
      nullptr, out116, nullptr, NV, 512);

  // ---- HE dual-weight GEMM: HEh16/HEt16 (into hsum region; hsum dead) ----
  k_gemm<AF16D, EP_HE2><<<(NV + 63) / 64, 256, 0, stream>>>(
      out016, out116, nullptr, nullptr, Whehf, Whetf, nullptr, nullptr,
      nullptr, HEh16, HEt16, NV, 512);

  // ---- lean edge combine ----
  k_edge<<<E / 4, 256, 0, stream>>>(ea2q16, HEh16, HEt16, ei32, pW2, pb2, noise,
                                    (float*)d_out);
}